// Round 2
// baseline (367.348 us; speedup 1.0000x reference)
//
#include <hip/hip_runtime.h>
#include <math.h>

// Problem constants (from reference): B=32, S=2048, D=1024, fp32 in/out.
#define BD 32
#define SD 2048
#define DD 1024
#define MASK_PENALTY 100000000.0f
#define NTHREADS 256
#define NW 4   // waves per block
#define UR 2   // rows per wave processed together (ILP for the butterfly)

// Kernel 1: per (batch, S-chunk) partial online-softmax attention.
// Each WAVE owns whole rows (lane i holds d = lane*4 + 256*j, j=0..3), so the
// dot reduction is wave-internal (butterfly) -- no LDS, no per-iteration
// barriers. The 4 waves merge (m,l,o) ONCE at block end (2 barriers total).
__global__ __launch_bounds__(NTHREADS, 4) void attn_partial(
    const float* __restrict__ target,   // [B,D]
    const float* __restrict__ context,  // [B,S,D]
    const float* __restrict__ mask,     // [B,S]
    float* __restrict__ wsO,            // [B*C, D]
    float* __restrict__ wsM,            // [B*C]
    float* __restrict__ wsL,            // [B*C]
    int C)
{
    const int g = blockIdx.x;
    const int b = g / C;
    const int c = g % C;
    const int rows = SD / C;            // rows per block (64 at C=32)
    const int s0 = c * rows;
    const int t = threadIdx.x;
    const int lane = t & 63;
    const int w = t >> 6;

    // query fragment: lane owns d = lane*4 + 256*j
    float4 tgt[4];
    #pragma unroll
    for (int j = 0; j < 4; ++j)
        tgt[j] = *(const float4*)(target + (size_t)b * DD + j * 256 + lane * 4);

    const int rpw = rows / NW;          // rows per wave (16)
    const int r0 = w * rpw;
    const float* ctx = context + ((size_t)b * SD + s0 + r0) * DD + lane * 4;
    const float* mk  = mask + (size_t)b * SD + s0 + r0;

    float4 o[4];
    #pragma unroll
    for (int j = 0; j < 4; ++j) o[j] = make_float4(0.f, 0.f, 0.f, 0.f);
    float m = -INFINITY, l = 0.f;

    for (int i = 0; i < rpw; i += UR) {
        // one read of context kept in registers for both dot and accumulation
        float4 x[UR][4];
        #pragma unroll
        for (int r = 0; r < UR; ++r) {
            const float* rp = ctx + (size_t)(i + r) * DD;
            #pragma unroll
            for (int j = 0; j < 4; ++j)
                x[r][j] = *(const float4*)(rp + j * 256);
        }
        float sc[UR];
        #pragma unroll
        for (int r = 0; r < UR; ++r) {
            float s = 0.f;
            #pragma unroll
            for (int j = 0; j < 4; ++j) {
                s = fmaf(x[r][j].x, tgt[j].x, s);
                s = fmaf(x[r][j].y, tgt[j].y, s);
                s = fmaf(x[r][j].z, tgt[j].z, s);
                s = fmaf(x[r][j].w, tgt[j].w, s);
            }
            sc[r] = s;
        }
        // wave-internal butterfly, UR rows interleaved for ILP
        #pragma unroll
        for (int off = 32; off > 0; off >>= 1) {
            #pragma unroll
            for (int r = 0; r < UR; ++r)
                sc[r] += __shfl_xor(sc[r], off);
        }
        #pragma unroll
        for (int r = 0; r < UR; ++r)
            sc[r] += (mk[i + r] - 1.0f) * MASK_PENALTY;

        // online-softmax update
        float mnew = m;
        #pragma unroll
        for (int r = 0; r < UR; ++r) mnew = fmaxf(mnew, sc[r]);
        const float alpha = __expf(m - mnew);   // m=-inf first iter -> 0
        float p[UR], ps = 0.f;
        #pragma unroll
        for (int r = 0; r < UR; ++r) { p[r] = __expf(sc[r] - mnew); ps += p[r]; }
        l = l * alpha + ps;
        #pragma unroll
        for (int j = 0; j < 4; ++j) {
            o[j].x *= alpha; o[j].y *= alpha; o[j].z *= alpha; o[j].w *= alpha;
            #pragma unroll
            for (int r = 0; r < UR; ++r) {
                o[j].x = fmaf(p[r], x[r][j].x, o[j].x);
                o[j].y = fmaf(p[r], x[r][j].y, o[j].y);
                o[j].z = fmaf(p[r], x[r][j].z, o[j].z);
                o[j].w = fmaf(p[r], x[r][j].w, o[j].w);
            }
        }
        m = mnew;
    }

    // ---- block-level merge of the 4 per-wave partials (2 barriers total) ----
    __shared__ float sM[NW];
    __shared__ float sL[NW];
    __shared__ float sO[NW][DD];        // 16 KB
    if (lane == 0) { sM[w] = m; sL[w] = l; }
    __syncthreads();
    float M = fmaxf(fmaxf(sM[0], sM[1]), fmaxf(sM[2], sM[3]));
    float lsum = 0.f;
    #pragma unroll
    for (int ww = 0; ww < NW; ++ww) lsum += sL[ww] * __expf(sM[ww] - M);
    const float aw = __expf(m - M);     // m is uniform across the wave
    #pragma unroll
    for (int j = 0; j < 4; ++j) {
        float4 v = make_float4(o[j].x * aw, o[j].y * aw, o[j].z * aw, o[j].w * aw);
        *(float4*)(&sO[w][j * 256 + lane * 4]) = v;
    }
    __syncthreads();
    // thread t owns output d-range [t*4, t*4+4)
    float4 acc = make_float4(0.f, 0.f, 0.f, 0.f);
    #pragma unroll
    for (int ww = 0; ww < NW; ++ww) {
        float4 v = *(const float4*)(&sO[ww][t * 4]);
        acc.x += v.x; acc.y += v.y; acc.z += v.z; acc.w += v.w;
    }
    *(float4*)(wsO + (size_t)g * DD + t * 4) = acc;
    if (t == 0) { wsM[g] = M; wsL[g] = lsum; }
}

// Kernel 2: combine C partials per batch with global max rescaling.
__global__ __launch_bounds__(NTHREADS) void attn_combine(
    const float* __restrict__ wsO,
    const float* __restrict__ wsM,
    const float* __restrict__ wsL,
    float* __restrict__ out,
    int C)
{
    const int b = blockIdx.x;
    const int t = threadIdx.x;
    __shared__ float wgt[64];           // per-chunk normalized weights (C <= 64)

    if (t < 64) {
        float mv = (t < C) ? wsM[b * C + t] : -INFINITY;
        float mred = mv;
        #pragma unroll
        for (int off = 32; off > 0; off >>= 1)
            mred = fmaxf(mred, __shfl_xor(mred, off));
        float lw = (t < C) ? wsL[b * C + t] * __expf(mv - mred) : 0.f;
        float lsum = lw;
        #pragma unroll
        for (int off = 32; off > 0; off >>= 1)
            lsum += __shfl_xor(lsum, off);
        wgt[t] = (t < C) ? __expf(mv - mred) / lsum : 0.f;
    }
    __syncthreads();

    float4 acc = make_float4(0.f, 0.f, 0.f, 0.f);
    for (int c = 0; c < C; ++c) {
        float4 v = *(const float4*)(wsO + ((size_t)(b * C + c)) * DD + t * 4);
        float wc = wgt[c];
        acc.x = fmaf(wc, v.x, acc.x); acc.y = fmaf(wc, v.y, acc.y);
        acc.z = fmaf(wc, v.z, acc.z); acc.w = fmaf(wc, v.w, acc.w);
    }
    *(float4*)(out + (size_t)b * DD + t * 4) = acc;
}

extern "C" void kernel_launch(void* const* d_in, const int* in_sizes, int n_in,
                              void* d_out, int out_size, void* d_ws, size_t ws_size,
                              hipStream_t stream) {
    const float* target  = (const float*)d_in[0];  // [B,D]
    const float* context = (const float*)d_in[1];  // [B,S,D]
    const float* mask    = (const float*)d_in[2];  // [B,S]
    float* out = (float*)d_out;                    // [B,D]

    // chunks per batch: 32 -> 1024 blocks (4/CU). Fall back if ws too small.
    int C = 32;
    while (C > 1 && (size_t)BD * C * (DD + 2) * sizeof(float) > ws_size) C >>= 1;

    float* wsO = (float*)d_ws;                 // [B*C, D]
    float* wsM = wsO + (size_t)BD * C * DD;    // [B*C]
    float* wsL = wsM + (size_t)BD * C;         // [B*C]

    attn_partial<<<BD * C, NTHREADS, 0, stream>>>(target, context, mask, wsO, wsM, wsL, C);
    attn_combine<<<BD, NTHREADS, 0, stream>>>(wsO, wsM, wsL, out, C);
}

// Round 3
// 339.283 us; speedup vs baseline: 1.0827x; 1.0827x over previous
//
#include <hip/hip_runtime.h>
#include <math.h>
#include <float.h>

// Problem constants (from reference): B=32, S=2048, D=1024, fp32 in/out.
#define BD 32
#define SD 2048
#define DD 1024
#define MASK_PENALTY 100000000.0f
#define NTHREADS 256
#define NW 4   // waves per block

// Kernel 1: per (batch, S-chunk) partial online-softmax attention.
// Each WAVE owns whole rows (lane i holds d = lane*4 + 256*j, j=0..3): dot
// reduction is a wave-internal butterfly, no per-row barriers.
// KEY: masked rows (mask==0) have softmax weight exp(-1e8 - m) == 0.0f
// exactly in fp32, so they are SKIPPED without loading their 4 KB context
// row -- the branch is wave-uniform (zero divergence), halving HBM traffic.
__global__ __launch_bounds__(NTHREADS, 4) void attn_partial(
    const float* __restrict__ target,   // [B,D]
    const float* __restrict__ context,  // [B,S,D]
    const float* __restrict__ mask,     // [B,S]
    float* __restrict__ wsO,            // [B*C, D]
    float* __restrict__ wsM,            // [B*C]
    float* __restrict__ wsL,            // [B*C]
    int C)
{
    const int g = blockIdx.x;
    const int b = g / C;
    const int c = g % C;
    const int rows = SD / C;            // rows per block (32 at C=64)
    const int s0 = c * rows;
    const int t = threadIdx.x;
    const int lane = t & 63;
    const int w = t >> 6;

    // query fragment: lane owns d = lane*4 + 256*j
    float4 tgt[4];
    #pragma unroll
    for (int j = 0; j < 4; ++j)
        tgt[j] = *(const float4*)(target + (size_t)b * DD + j * 256 + lane * 4);

    const int rpw = rows / NW;          // rows per wave (8 at C=64)
    const int r0 = w * rpw;
    const float* ctx = context + ((size_t)b * SD + s0 + r0) * DD + lane * 4;
    const float* mk  = mask + (size_t)b * SD + s0 + r0;

    // one coalesced load of this wave's mask values; broadcast by __shfl
    float mlane = (lane < rpw) ? mk[lane] : 0.f;

    float4 o[4];
    #pragma unroll
    for (int j = 0; j < 4; ++j) o[j] = make_float4(0.f, 0.f, 0.f, 0.f);
    // -FLT_MAX (not -INF) sentinel: empty waves/chunks produce clean zeros
    // (exp(-FLT_MAX - x) == 0, exp(-FLT_MAX + FLT_MAX) == 1) -- no NaN paths.
    float m = -FLT_MAX, l = 0.f;

    for (int i = 0; i < rpw; ++i) {
        const float mv = __shfl(mlane, i);
        if (mv == 0.f) continue;        // wave-uniform skip: no context load
        const float* rp = ctx + (size_t)i * DD;
        float4 x[4];
        #pragma unroll
        for (int j = 0; j < 4; ++j)
            x[j] = *(const float4*)(rp + j * 256);
        float s = 0.f;
        #pragma unroll
        for (int j = 0; j < 4; ++j) {
            s = fmaf(x[j].x, tgt[j].x, s);
            s = fmaf(x[j].y, tgt[j].y, s);
            s = fmaf(x[j].z, tgt[j].z, s);
            s = fmaf(x[j].w, tgt[j].w, s);
        }
        #pragma unroll
        for (int off = 32; off > 0; off >>= 1)
            s += __shfl_xor(s, off);
        // mv == 1 here, so (mv-1)*MASK_PENALTY == 0: no penalty term needed
        const float mnew = fmaxf(m, s);
        const float alpha = __expf(m - mnew);   // 0 on first valid row
        const float p = __expf(s - mnew);
        l = l * alpha + p;
        #pragma unroll
        for (int j = 0; j < 4; ++j) {
            o[j].x = fmaf(o[j].x, alpha, p * x[j].x);
            o[j].y = fmaf(o[j].y, alpha, p * x[j].y);
            o[j].z = fmaf(o[j].z, alpha, p * x[j].z);
            o[j].w = fmaf(o[j].w, alpha, p * x[j].w);
        }
        m = mnew;
    }

    // ---- block-level merge of the 4 per-wave partials (2 barriers total) ----
    __shared__ float sM[NW];
    __shared__ float sL[NW];
    __shared__ float sO[NW][DD];        // 16 KB
    if (lane == 0) { sM[w] = m; sL[w] = l; }
    __syncthreads();
    const float M = fmaxf(fmaxf(sM[0], sM[1]), fmaxf(sM[2], sM[3]));
    float lsum = 0.f;
    #pragma unroll
    for (int ww = 0; ww < NW; ++ww) lsum += sL[ww] * __expf(sM[ww] - M);
    const float aw = __expf(m - M);     // m wave-uniform; 1 if both -FLT_MAX
    #pragma unroll
    for (int j = 0; j < 4; ++j) {
        float4 v = make_float4(o[j].x * aw, o[j].y * aw, o[j].z * aw, o[j].w * aw);
        *(float4*)(&sO[w][j * 256 + lane * 4]) = v;
    }
    __syncthreads();
    float4 acc = make_float4(0.f, 0.f, 0.f, 0.f);
    #pragma unroll
    for (int ww = 0; ww < NW; ++ww) {
        float4 v = *(const float4*)(&sO[ww][t * 4]);
        acc.x += v.x; acc.y += v.y; acc.z += v.z; acc.w += v.w;
    }
    *(float4*)(wsO + (size_t)g * DD + t * 4) = acc;
    if (t == 0) { wsM[g] = M; wsL[g] = lsum; }
}

// Kernel 2: combine C partials per batch with global max rescaling.
// Grid = B * 4 blocks; each block owns a 256-element d-quarter of one batch.
__global__ __launch_bounds__(NTHREADS) void attn_combine(
    const float* __restrict__ wsO,
    const float* __restrict__ wsM,
    const float* __restrict__ wsL,
    float* __restrict__ out,
    int C)
{
    const int bb = blockIdx.x;
    const int b = bb >> 2;
    const int d0 = (bb & 3) * 256;
    const int t = threadIdx.x;
    __shared__ float wgt[64];           // per-chunk normalized weights (C <= 64)

    if (t < 64) {
        float mv = (t < C) ? wsM[b * C + t] : -FLT_MAX;
        float mred = mv;
        #pragma unroll
        for (int off = 32; off > 0; off >>= 1)
            mred = fmaxf(mred, __shfl_xor(mred, off));
        float lw = (t < C) ? wsL[b * C + t] * __expf(mv - mred) : 0.f;
        float lsum = lw;
        #pragma unroll
        for (int off = 32; off > 0; off >>= 1)
            lsum += __shfl_xor(lsum, off);
        wgt[t] = (t < C) ? __expf(mv - mred) / lsum : 0.f;
    }
    __syncthreads();

    float acc = 0.f;
    for (int c = 0; c < C; ++c)
        acc = fmaf(wgt[c], wsO[((size_t)(b * C + c)) * DD + d0 + t], acc);
    out[(size_t)b * DD + d0 + t] = acc;
}

extern "C" void kernel_launch(void* const* d_in, const int* in_sizes, int n_in,
                              void* d_out, int out_size, void* d_ws, size_t ws_size,
                              hipStream_t stream) {
    const float* target  = (const float*)d_in[0];  // [B,D]
    const float* context = (const float*)d_in[1];  // [B,S,D]
    const float* mask    = (const float*)d_in[2];  // [B,S]
    float* out = (float*)d_out;                    // [B,D]

    // chunks per batch: 64 -> 2048 blocks (~8/CU for dynamic balancing of
    // the random mask skips). Fall back if ws too small.
    int C = 64;
    while (C > 1 && (size_t)BD * C * (DD + 2) * sizeof(float) > ws_size) C >>= 1;

    float* wsO = (float*)d_ws;                 // [B*C, D]
    float* wsM = wsO + (size_t)BD * C * DD;    // [B*C]
    float* wsL = wsM + (size_t)BD * C;         // [B*C]

    attn_partial<<<BD * C, NTHREADS, 0, stream>>>(target, context, mask, wsO, wsM, wsL, C);
    attn_combine<<<BD * 4, NTHREADS, 0, stream>>>(wsO, wsM, wsL, out, C);
}